// Round 3
// baseline (253.231 us; speedup 1.0000x reference)
//
#include <hip/hip_runtime.h>

// WiSARD: ENTRY=1024, TUPLE=16, NCLS=10, BATCH=4096
#define B_TOT   4096
#define E_SZ    1024
#define T_SZ    16
#define N_CLS   10
#define N_NEU   64                      // ENTRY / TUPLE
#define N_ADDR  65536                   // 2^TUPLE
#define RWORDS  (N_ADDR / 32)           // 2048 u32 words per neuron bitmask
#define RAMBITS_WORDS (N_CLS * N_NEU * RWORDS)   // 1,310,720 (5.24 MB)
#define SBITS_WORDS   (B_TOT * (E_SZ / 32))      // 131,072   (512 KB)
#define RAM_BLOCKS    (RAMBITS_WORDS / 256)      // 5120
#define SB_BLOCKS     (SBITS_WORDS / 256)        // 512

// ---- fused packer: blocks [0,5120) pack ram (f32 0/1 -> bits),
//      blocks [5120,5632) pack samples (i32 0/1 -> bits). HBM-bound:
//      streams 184.6 MB of inputs once, coalesced float4/int4.
__global__ __launch_bounds__(256) void pack_all(const float* __restrict__ ram,
                                                const int* __restrict__ samples,
                                                unsigned* __restrict__ rambits,
                                                unsigned* __restrict__ sbits) {
    int blk = blockIdx.x;
    int tid = threadIdx.x;
    if (blk < RAM_BLOCKS) {
        int word = blk * 256 + tid;
        const float4* in4 = (const float4*)ram;
        unsigned w = 0;
#pragma unroll
        for (int j = 0; j < 8; ++j) {
            float4 v = in4[(size_t)word * 8 + j];
            w |= (v.x != 0.0f ? 1u : 0u) << (4 * j + 0);
            w |= (v.y != 0.0f ? 1u : 0u) << (4 * j + 1);
            w |= (v.z != 0.0f ? 1u : 0u) << (4 * j + 2);
            w |= (v.w != 0.0f ? 1u : 0u) << (4 * j + 3);
        }
        rambits[word] = w;
    } else {
        int word = (blk - RAM_BLOCKS) * 256 + tid;
        const int4* in4 = (const int4*)samples;
        unsigned w = 0;
#pragma unroll
        for (int j = 0; j < 8; ++j) {
            int4 v = in4[(size_t)word * 8 + j];
            w |= (v.x != 0 ? 1u : 0u) << (4 * j + 0);
            w |= (v.y != 0 ? 1u : 0u) << (4 * j + 1);
            w |= (v.z != 0 ? 1u : 0u) << (4 * j + 2);
            w |= (v.w != 0 ? 1u : 0u) << (4 * j + 3);
        }
        sbits[word] = w;
    }
}

// ---- main: block = (class c, 64-batch tile), 512 threads = 8 waves
// (20 waves/CU at 640 blocks -> good probe-latency hiding).
// lane = local b; wave wv owns neurons [wv*8, wv*8+8) -> tmap/ram pointers
// wave-uniform (scalar pipe). smp rows padded to 33 words: bank =
// (lane+word)%32, exactly 2-way aliasing across 64 lanes = free.
__global__ __launch_bounds__(512) void wisard_main(const unsigned* __restrict__ sbits,
                                                   const int* __restrict__ tmap,
                                                   const unsigned* __restrict__ rambits,
                                                   float* __restrict__ out) {
    __shared__ unsigned smp[64 * 33];
    __shared__ int red[512];

    // XCD-aware swizzle: 640 blocks / 8 XCDs -> contiguous 80-work chunks,
    // so each XCD's L2 holds ~1.25 classes (~650 KB) of the bit table.
    int bid  = blockIdx.x;
    int work = (bid & 7) * 80 + (bid >> 3);
    int c     = work >> 6;
    int btile = work & 63;
    int tid = threadIdx.x;

    for (int i = tid; i < 64 * 32; i += 512) {
        int bl = i >> 5, w = i & 31;
        smp[bl * 33 + w] = sbits[(btile * 64 + bl) * 32 + w];
    }
    __syncthreads();

    int lane = tid & 63;
    int base = __builtin_amdgcn_readfirstlane((tid >> 6) * 8);   // first neuron
    const int* tw = tmap + c * 1024 + base * 16;                 // 8 neurons x 16
    const unsigned* ramw = rambits + ((size_t)c << 17) + ((size_t)base << 11);
    unsigned row = (unsigned)(lane * 33);

    int acc = 0;
    for (int nn = 0; nn < 8; ++nn) {
        unsigned addr = 0;
#pragma unroll
        for (int t = 0; t < 16; ++t) {
            int e = tw[nn * 16 + t];           // s_load (scalar pipe)
            unsigned s = smp[row + (unsigned)(e >> 5)];
            addr = (addr << 1) | ((s >> (e & 31)) & 1u);
        }
        unsigned wrd = ramw[(nn << 11) + (addr >> 5)];   // L2-resident probe
        acc += (int)((wrd >> (addr & 31u)) & 1u);
    }

    red[tid] = acc;
    __syncthreads();
    if (tid < 64) {
        int s = 0;
#pragma unroll
        for (int k = 0; k < 8; ++k) s += red[tid + 64 * k];
        out[(btile * 64 + tid) * N_CLS + c] = (float)s;
    }
}

extern "C" void kernel_launch(void* const* d_in, const int* in_sizes, int n_in,
                              void* d_out, int out_size, void* d_ws, size_t ws_size,
                              hipStream_t stream) {
    const int*   samples = (const int*)d_in[0];    // [4096,1024] 0/1
    const int*   tmap    = (const int*)d_in[1];    // [10,1024] permutations
    const float* ram     = (const float*)d_in[2];  // [10,64,65536] 0/1

    float* out = (float*)d_out;                    // [4096,10]

    unsigned* rambits = (unsigned*)d_ws;                   // 5.24 MB
    unsigned* sbits   = rambits + RAMBITS_WORDS;           // +512 KB

    pack_all<<<RAM_BLOCKS + SB_BLOCKS, 256, 0, stream>>>(ram, samples, rambits, sbits);
    wisard_main<<<640, 512, 0, stream>>>(sbits, tmap, rambits, out);
}